// Round 16
// baseline (228.348 us; speedup 1.0000x reference)
//
#include <hip/hip_runtime.h>
#include <hip/hip_bf16.h>

#define N_TOT 8192
#define BHALF 4096
#define DIM   256
#define INV_T 2.0f   // 1/temperature
#define NTILES 2080  // 64*65/2 upper-triangular 128x128 tiles

typedef __attribute__((ext_vector_type(8))) short bf16x8;
typedef __attribute__((ext_vector_type(4))) float f32x4;

__device__ __forceinline__ float b2f(unsigned short u) {
  union { unsigned u; float f; } cv; cv.u = ((unsigned)u) << 16; return cv.f;
}
__device__ __forceinline__ unsigned short f2b(float f) {
  union { float f; unsigned u; } cv; cv.f = f;
  unsigned u = cv.u;
  u += 0x7FFFu + ((u >> 16) & 1u);  // round-to-nearest-even
  return (unsigned short)(u >> 16);
}

// ---------------------------------------------------------------------------
// Kernel 1: L2-normalize rows of [e_i; e_j] -> bf16 zn[8192][256]
// one wave per row; also zeroes S and the completion counter (replaces memset)
// ---------------------------------------------------------------------------
__global__ __launch_bounds__(256) void normalize_kernel(
    const float* __restrict__ ei, const float* __restrict__ ej,
    unsigned short* __restrict__ zn, float* __restrict__ S,
    unsigned* __restrict__ counter) {
  if (threadIdx.x < 4) S[blockIdx.x * 4 + threadIdx.x] = 0.f;
  if (blockIdx.x == 0 && threadIdx.x == 0) *counter = 0u;
  const int wave = threadIdx.x >> 6, lane = threadIdx.x & 63;
  const int row = blockIdx.x * 4 + wave;
  const float* src = (row < BHALF) ? (ei + (size_t)row * DIM)
                                   : (ej + (size_t)(row - BHALF) * DIM);
  float4 v = *reinterpret_cast<const float4*>(src + lane * 4);
  float ss = v.x * v.x + v.y * v.y + v.z * v.z + v.w * v.w;
#pragma unroll
  for (int off = 32; off; off >>= 1) ss += __shfl_xor(ss, off, 64);
  float inv = rsqrtf(ss);
  ushort4 o;
  o.x = f2b(v.x * inv); o.y = f2b(v.y * inv);
  o.z = f2b(v.z * inv); o.w = f2b(v.w * inv);
  *reinterpret_cast<ushort4*>(zn + (size_t)row * DIM + lane * 4) = o;
}

// ---------------------------------------------------------------------------
// Kernel 2: upper-triangular tiles, 2-phase double-buffered staging (T3-min),
// exp epilogue with row+column scatter (symmetry), p extraction, and fused
// last-block finalize (loss -> out[0]).
// ---------------------------------------------------------------------------
__global__ __launch_bounds__(256) void simexp_kernel(
    const unsigned short* __restrict__ zn, float* __restrict__ S,
    float* __restrict__ p, unsigned* __restrict__ counter,
    float* __restrict__ out) {
  __shared__ __align__(16) unsigned short As[2][128 * 64];
  __shared__ __align__(16) unsigned short Bs[2][128 * 64];
  __shared__ float red[4];
  __shared__ bool lastFlag;

  const int tid = threadIdx.x;
  const int wave = tid >> 6, lane = tid & 63;

  // decode linear block id -> (a,b), a<=b, row-major upper triangle
  int t = blockIdx.x;
  int a = 0;
  while ((a + 1) * 64 - ((a + 1) * a) / 2 <= t) ++a;
  const int b = a + (t - (a * 64 - (a * (a - 1)) / 2));
  const bool offdiag = (b != a);
  const bool need_p = (b == a + 32);

  const int wr = wave >> 1, wc = wave & 1;

  f32x4 acc[4][4] = {};

  const int fragrow_a = wr * 64 + (lane & 15);
  const int fragrow_b = wc * 64 + (lane & 15);
  const int kcolb = (lane >> 4) * 16;

  const unsigned short* gA = zn + (size_t)a * 128 * DIM;
  const unsigned short* gB = zn + (size_t)b * 128 * DIM;

  const int lrow  = lane >> 3;        // row within 8-row chunk
  const int lslot = (lane & 7) * 16;  // linear 16B slot within row

#define STAGE(nb, kt_) do {                                                   \
    _Pragma("unroll")                                                         \
    for (int r = 0; r < 4; ++r) {                                             \
      const int c = wave * 4 + r;                                             \
      const int row = c * 8 + lrow;                                           \
      const int colb = lslot ^ ((row & 7) << 4);                              \
      const unsigned short* sA = gA + (size_t)row * DIM + (kt_) * 64 + (colb >> 1); \
      const unsigned short* sB = gB + (size_t)row * DIM + (kt_) * 64 + (colb >> 1); \
      __builtin_amdgcn_global_load_lds(                                       \
          (const __attribute__((address_space(1))) void*)sA,                  \
          (__attribute__((address_space(3))) void*)(&As[nb][c * 512]), 16, 0, 0); \
      __builtin_amdgcn_global_load_lds(                                       \
          (const __attribute__((address_space(1))) void*)sB,                  \
          (__attribute__((address_space(3))) void*)(&Bs[nb][c * 512]), 16, 0, 0); \
    }                                                                         \
  } while (0)

  STAGE(0, 0);
  __syncthreads();  // buf0 ready (vmcnt(0) drain + barrier)

  for (int kt = 0; kt < 4; ++kt) {
    const int cur = kt & 1;
    if (kt < 3) STAGE(cur ^ 1, kt + 1);  // prefetch next tile FIRST

#pragma unroll
    for (int ks = 0; ks < 2; ++ks) {
      bf16x8 af[4], bfr[4];
#pragma unroll
      for (int m = 0; m < 4; ++m) {
        const int row = fragrow_a + m * 16;
        const int byt = row * 128 + ((ks * 64 + kcolb) ^ ((row & 7) << 4));
        af[m] = *reinterpret_cast<const bf16x8*>(
            reinterpret_cast<const char*>(&As[cur][0]) + byt);
      }
#pragma unroll
      for (int n = 0; n < 4; ++n) {
        const int row = fragrow_b + n * 16;
        const int byt = row * 128 + ((ks * 64 + kcolb) ^ ((row & 7) << 4));
        bfr[n] = *reinterpret_cast<const bf16x8*>(
            reinterpret_cast<const char*>(&Bs[cur][0]) + byt);
      }
#pragma unroll
      for (int m = 0; m < 4; ++m)
#pragma unroll
        for (int n = 0; n < 4; ++n)
          acc[m][n] = __builtin_amdgcn_mfma_f32_16x16x32_bf16(
              af[m], bfr[n], acc[m][n], 0, 0, 0);
    }
    __syncthreads();  // drains vmcnt(0): next buf ready; protects buffer reuse
  }
#undef STAGE

  // ---- epilogue ----
  const int grow0 = a * 128 + wr * 64 + (lane >> 4) * 4;  // + m*16 + r
  const int gcol0 = b * 128 + wc * 64 + (lane & 15);      // + n*16

  // phase 1: posdot extract (raw, device-coherent), exp in place, diag mask
#pragma unroll
  for (int m = 0; m < 4; ++m)
#pragma unroll
    for (int n = 0; n < 4; ++n)
#pragma unroll
      for (int r = 0; r < 4; ++r) {
        const int gr = grow0 + m * 16 + r;
        const int gc = gcol0 + n * 16;
        const float raw = acc[m][n][r];
        if (need_p && gc == gr + BHALF) atomicExch(&p[gr], raw * INV_T);
        float v = __expf(raw * INV_T);
        if (gr == gc) v = 0.f;  // only possible on diagonal tiles
        acc[m][n][r] = v;
      }

  // phase 2: row sums -> S[rows of a]
#pragma unroll
  for (int m = 0; m < 4; ++m) {
    float rs[4];
#pragma unroll
    for (int r = 0; r < 4; ++r)
      rs[r] = acc[m][0][r] + acc[m][1][r] + acc[m][2][r] + acc[m][3][r];
#pragma unroll
    for (int off = 1; off < 16; off <<= 1) {
#pragma unroll
      for (int r = 0; r < 4; ++r) rs[r] += __shfl_xor(rs[r], off, 64);
    }
    if ((lane & 15) == 0) {
#pragma unroll
      for (int r = 0; r < 4; ++r)
        atomicAdd(&S[grow0 + m * 16 + r], rs[r]);
    }
  }

  // phase 3 (off-diagonal only): column sums -> S[rows of b] (symmetry)
  if (offdiag) {
#pragma unroll
    for (int n = 0; n < 4; ++n) {
      float cs = 0.f;
#pragma unroll
      for (int m = 0; m < 4; ++m)
#pragma unroll
        for (int r = 0; r < 4; ++r) cs += acc[m][n][r];
      cs += __shfl_xor(cs, 16, 64);
      cs += __shfl_xor(cs, 32, 64);
      if (lane < 16) atomicAdd(&S[gcol0 + n * 16], cs);
    }
  }

  // ---- fused finalize: last block computes the loss ----
  __syncthreads();   // all waves' atomics drained (vmcnt 0)
  __threadfence();
  if (tid == 0) lastFlag = (atomicAdd(counter, 1u) == NTILES - 1);
  __syncthreads();   // block-uniform flag
  if (lastFlag) {
    float accl = 0.f;
    for (int i = tid; i < N_TOT; i += 256) {
      const float Si = atomicAdd(&S[i], 0.f);                       // coherent read
      const float pi = atomicAdd(&p[(i < BHALF) ? i : i - BHALF], 0.f);
      accl += logf(Si) - pi;
    }
#pragma unroll
    for (int off = 32; off; off >>= 1) accl += __shfl_xor(accl, off, 64);
    if (lane == 0) red[wave] = accl;
    __syncthreads();
    if (tid == 0)
      out[0] = (red[0] + red[1] + red[2] + red[3]) / (float)N_TOT;
  }
}

// ---------------------------------------------------------------------------
extern "C" void kernel_launch(void* const* d_in, const int* in_sizes, int n_in,
                              void* d_out, int out_size, void* d_ws, size_t ws_size,
                              hipStream_t stream) {
  const float* ei = (const float*)d_in[0];
  const float* ej = (const float*)d_in[1];
  float* out = (float*)d_out;

  char* ws = (char*)d_ws;
  unsigned short* zn = (unsigned short*)ws;                            // 4 MiB
  float* S = (float*)(ws + (size_t)N_TOT * DIM * 2);                   // 32 KiB
  float* p = (float*)(ws + (size_t)N_TOT * DIM * 2 + N_TOT * 4);       // 16 KiB
  unsigned* counter = (unsigned*)(ws + (size_t)N_TOT * DIM * 2 + N_TOT * 8);

  normalize_kernel<<<N_TOT / 4, 256, 0, stream>>>(ei, ej, zn, S, counter);
  simexp_kernel<<<NTILES, 256, 0, stream>>>(zn, S, p, counter, out);
}

// Round 20
// 226.442 us; speedup vs baseline: 1.0084x; 1.0084x over previous
//
#include <hip/hip_runtime.h>
#include <hip/hip_bf16.h>

#define N_TOT 8192
#define BHALF 4096
#define DIM   256
#define INV_T 2.0f   // 1/temperature
#define NTILES 2080  // 64*65/2 upper-triangular 128x128 tiles

typedef __attribute__((ext_vector_type(8))) short bf16x8;
typedef __attribute__((ext_vector_type(4))) float f32x4;

__device__ __forceinline__ float b2f(unsigned short u) {
  union { unsigned u; float f; } cv; cv.u = ((unsigned)u) << 16; return cv.f;
}
__device__ __forceinline__ unsigned short f2b(float f) {
  union { float f; unsigned u; } cv; cv.f = f;
  unsigned u = cv.u;
  u += 0x7FFFu + ((u >> 16) & 1u);  // round-to-nearest-even
  return (unsigned short)(u >> 16);
}

// ---------------------------------------------------------------------------
// Kernel 1: L2-normalize rows of [e_i; e_j] -> bf16 zn[8192][256]
// one wave per row; also zeroes S and the completion counter (replaces memset)
// ---------------------------------------------------------------------------
__global__ __launch_bounds__(256) void normalize_kernel(
    const float* __restrict__ ei, const float* __restrict__ ej,
    unsigned short* __restrict__ zn, float* __restrict__ S,
    unsigned* __restrict__ counter) {
  if (threadIdx.x < 4) S[blockIdx.x * 4 + threadIdx.x] = 0.f;
  if (blockIdx.x == 0 && threadIdx.x == 0) *counter = 0u;
  const int wave = threadIdx.x >> 6, lane = threadIdx.x & 63;
  const int row = blockIdx.x * 4 + wave;
  const float* src = (row < BHALF) ? (ei + (size_t)row * DIM)
                                   : (ej + (size_t)(row - BHALF) * DIM);
  float4 v = *reinterpret_cast<const float4*>(src + lane * 4);
  float ss = v.x * v.x + v.y * v.y + v.z * v.z + v.w * v.w;
#pragma unroll
  for (int off = 32; off; off >>= 1) ss += __shfl_xor(ss, off, 64);
  float inv = rsqrtf(ss);
  ushort4 o;
  o.x = f2b(v.x * inv); o.y = f2b(v.y * inv);
  o.z = f2b(v.z * inv); o.w = f2b(v.w * inv);
  *reinterpret_cast<ushort4*>(zn + (size_t)row * DIM + lane * 4) = o;
}

// ---------------------------------------------------------------------------
// Kernel 2: upper-triangular tiles, SINGLE-buffered staging (r16 post-mortem:
// dbuf's 64.5 KiB LDS cut blocks/CU 5->2 and cost 3.2x — m132 failure mode).
// exp epilogue with row+column scatter (symmetry), p extraction, and fused
// last-block finalize (loss -> out[0]).
// ---------------------------------------------------------------------------
__global__ __launch_bounds__(256) void simexp_kernel(
    const unsigned short* __restrict__ zn, float* __restrict__ S,
    float* __restrict__ p, unsigned* __restrict__ counter,
    float* __restrict__ out) {
  __shared__ __align__(16) unsigned short As[128 * 64];
  __shared__ __align__(16) unsigned short Bs[128 * 64];
  __shared__ float red[4];
  __shared__ bool lastFlag;

  const int tid = threadIdx.x;
  const int wave = tid >> 6, lane = tid & 63;

  // decode linear block id -> (a,b), a<=b, row-major upper triangle
  int t = blockIdx.x;
  int a = 0;
  while ((a + 1) * 64 - ((a + 1) * a) / 2 <= t) ++a;
  const int b = a + (t - (a * 64 - (a * (a - 1)) / 2));
  const bool offdiag = (b != a);
  const bool need_p = (b == a + 32);

  const int wr = wave >> 1, wc = wave & 1;

  f32x4 acc[4][4] = {};

  const int fragrow_a = wr * 64 + (lane & 15);
  const int fragrow_b = wc * 64 + (lane & 15);
  const int kcolb = (lane >> 4) * 16;

  const unsigned short* gA = zn + (size_t)a * 128 * DIM;
  const unsigned short* gB = zn + (size_t)b * 128 * DIM;

  const int lrow  = lane >> 3;        // row within 8-row chunk
  const int lslot = (lane & 7) * 16;  // linear 16B slot within row

  for (int kt = 0; kt < 4; ++kt) {
#pragma unroll
    for (int r = 0; r < 4; ++r) {
      const int c = wave * 4 + r;
      const int row = c * 8 + lrow;
      const int colb = lslot ^ ((row & 7) << 4);  // inverse-swizzled source col
      const unsigned short* sA = gA + (size_t)row * DIM + kt * 64 + (colb >> 1);
      const unsigned short* sB = gB + (size_t)row * DIM + kt * 64 + (colb >> 1);
      __builtin_amdgcn_global_load_lds(
          (const __attribute__((address_space(1))) void*)sA,
          (__attribute__((address_space(3))) void*)(As + c * 512), 16, 0, 0);
      __builtin_amdgcn_global_load_lds(
          (const __attribute__((address_space(1))) void*)sB,
          (__attribute__((address_space(3))) void*)(Bs + c * 512), 16, 0, 0);
    }
    __syncthreads();  // drains vmcnt + barrier: tile ready

#pragma unroll
    for (int ks = 0; ks < 2; ++ks) {
      bf16x8 af[4], bfr[4];
#pragma unroll
      for (int m = 0; m < 4; ++m) {
        const int row = fragrow_a + m * 16;
        const int byt = row * 128 + ((ks * 64 + kcolb) ^ ((row & 7) << 4));
        af[m] = *reinterpret_cast<const bf16x8*>(
            reinterpret_cast<const char*>(As) + byt);
      }
#pragma unroll
      for (int n = 0; n < 4; ++n) {
        const int row = fragrow_b + n * 16;
        const int byt = row * 128 + ((ks * 64 + kcolb) ^ ((row & 7) << 4));
        bfr[n] = *reinterpret_cast<const bf16x8*>(
            reinterpret_cast<const char*>(Bs) + byt);
      }
#pragma unroll
      for (int m = 0; m < 4; ++m)
#pragma unroll
        for (int n = 0; n < 4; ++n)
          acc[m][n] = __builtin_amdgcn_mfma_f32_16x16x32_bf16(
              af[m], bfr[n], acc[m][n], 0, 0, 0);
    }
    __syncthreads();  // protect buffer overwrite next kt
  }

  // ---- epilogue ----
  const int grow0 = a * 128 + wr * 64 + (lane >> 4) * 4;  // + m*16 + r
  const int gcol0 = b * 128 + wc * 64 + (lane & 15);      // + n*16

  // phase 1: posdot extract (raw, device-coherent), exp in place, diag mask
#pragma unroll
  for (int m = 0; m < 4; ++m)
#pragma unroll
    for (int n = 0; n < 4; ++n)
#pragma unroll
      for (int r = 0; r < 4; ++r) {
        const int gr = grow0 + m * 16 + r;
        const int gc = gcol0 + n * 16;
        const float raw = acc[m][n][r];
        if (need_p && gc == gr + BHALF) atomicExch(&p[gr], raw * INV_T);
        float v = __expf(raw * INV_T);
        if (gr == gc) v = 0.f;  // only possible on diagonal tiles
        acc[m][n][r] = v;
      }

  // phase 2: row sums -> S[rows of a]
#pragma unroll
  for (int m = 0; m < 4; ++m) {
    float rs[4];
#pragma unroll
    for (int r = 0; r < 4; ++r)
      rs[r] = acc[m][0][r] + acc[m][1][r] + acc[m][2][r] + acc[m][3][r];
#pragma unroll
    for (int off = 1; off < 16; off <<= 1) {
#pragma unroll
      for (int r = 0; r < 4; ++r) rs[r] += __shfl_xor(rs[r], off, 64);
    }
    if ((lane & 15) == 0) {
#pragma unroll
      for (int r = 0; r < 4; ++r)
        atomicAdd(&S[grow0 + m * 16 + r], rs[r]);
    }
  }

  // phase 3 (off-diagonal only): column sums -> S[rows of b] (symmetry)
  if (offdiag) {
#pragma unroll
    for (int n = 0; n < 4; ++n) {
      float cs = 0.f;
#pragma unroll
      for (int m = 0; m < 4; ++m)
#pragma unroll
        for (int r = 0; r < 4; ++r) cs += acc[m][n][r];
      cs += __shfl_xor(cs, 16, 64);
      cs += __shfl_xor(cs, 32, 64);
      if (lane < 16) atomicAdd(&S[gcol0 + n * 16], cs);
    }
  }

  // ---- fused finalize: last block computes the loss ----
  __syncthreads();   // all waves' atomics drained (vmcnt 0)
  __threadfence();
  if (tid == 0) lastFlag = (atomicAdd(counter, 1u) == NTILES - 1);
  __syncthreads();   // block-uniform flag
  if (lastFlag) {
    float accl = 0.f;
    for (int i = tid; i < N_TOT; i += 256) {
      const float Si = atomicAdd(&S[i], 0.f);                       // coherent read
      const float pi = atomicAdd(&p[(i < BHALF) ? i : i - BHALF], 0.f);
      accl += logf(Si) - pi;
    }
#pragma unroll
    for (int off = 32; off; off >>= 1) accl += __shfl_xor(accl, off, 64);
    if (lane == 0) red[wave] = accl;
    __syncthreads();
    if (tid == 0)
      out[0] = (red[0] + red[1] + red[2] + red[3]) / (float)N_TOT;
  }
}

// ---------------------------------------------------------------------------
extern "C" void kernel_launch(void* const* d_in, const int* in_sizes, int n_in,
                              void* d_out, int out_size, void* d_ws, size_t ws_size,
                              hipStream_t stream) {
  const float* ei = (const float*)d_in[0];
  const float* ej = (const float*)d_in[1];
  float* out = (float*)d_out;

  char* ws = (char*)d_ws;
  unsigned short* zn = (unsigned short*)ws;                            // 4 MiB
  float* S = (float*)(ws + (size_t)N_TOT * DIM * 2);                   // 32 KiB
  float* p = (float*)(ws + (size_t)N_TOT * DIM * 2 + N_TOT * 4);       // 16 KiB
  unsigned* counter = (unsigned*)(ws + (size_t)N_TOT * DIM * 2 + N_TOT * 8);

  normalize_kernel<<<N_TOT / 4, 256, 0, stream>>>(ei, ej, zn, S, counter);
  simexp_kernel<<<NTILES, 256, 0, stream>>>(zn, S, p, counter, out);
}